// Round 8
// baseline (88.934 us; speedup 1.0000x reference)
//
#include <hip/hip_runtime.h>
#include <stdint.h>

// GCMConv on MI355X. Data model (verified rounds 0-3):
//   x      : float32 (1,16384,8,3,3,2)  — complex pair = float2
//   weight : float32 (4,9,33)
//   out    : float32 (1,16384,8,3,3,2)
//
// out[u] = sum_{w16<16} ( N1 @ t[w16] + N2 @ t[w16]^+ ) + N(w=32)
//   Nk = sum_v weight[u,v,wk] * w_full[v],  w_full = [w0..3, w0..3^+, I].
//
// 16 threads per site (u=out-channel, g=w16-quarter); shfl_xor reduce over g.
// Round-8: all complex arithmetic as float2 element-wise FMA so LLVM can emit
// v_pk_fma_f32 (2 fp32 FMA/lane/inst on CDNA4). (re,im) always share a scalar
// multiplier; conjugation/dagger = per-component neg + swizzle, which packed
// ops express via neg_lo/neg_hi/opsel. Static VALU-FMA count ~halves.

#define SPB 16            // sites per block
#define TPB 256           // 16 threads per site
#define NSITES 16384
#define TS2_SITE 146      // float2 units per site: 16*9 + 2 pad
#define NWGT 1188         // 4*9*33

__device__ __forceinline__ float2 pk_fma(float2 a, float2 b, float2 c){
    return make_float2(fmaf(a.x, b.x, c.x), fmaf(a.y, b.y, c.y));
}
__device__ __forceinline__ float2 spl(float s){ return make_float2(s, s); }
__device__ __forceinline__ float2 pn(float s){ return make_float2(s, -s); }   // (+s,-s)
__device__ __forceinline__ float2 np(float s){ return make_float2(-s, s); }   // (-s,+s)
__device__ __forceinline__ float2 swp(float2 a){ return make_float2(a.y, a.x); }

__device__ __forceinline__ int neigh(int s, int a){
    // dims (8,8,16,16): d3 bits[0:4), d2 bits[4:8), d1 bits[8:11), d0 bits[11:14)
    if (a == 3) return (s & ~15)        | ((s + 1)    & 15);
    if (a == 2) return (s & ~(15 << 4)) | ((s + 16)   & (15 << 4));
    if (a == 1) return (s & ~(7 << 8))  | ((s + 256)  & (7 << 8));
    return              (s & ~(7 << 11))| ((s + 2048) & (7 << 11));
}

__global__ __launch_bounds__(TPB, 1)
void gcm_fused(const float* __restrict__ xp,
               const float* __restrict__ wgt,
               float* __restrict__ outp)
{
    __shared__ float2 lt[SPB * TS2_SITE];
    __shared__ float wsm[NWGT];
    const float2* x2 = (const float2*)xp;
    float2* o2 = (float2*)outp;

    const int tid = threadIdx.x;
    const int g   = tid & 3;            // lane bits 0-1 -> shfl_xor reduction
    const int u   = (tid >> 2) & 3;     // output channel / phase1 axis
    const int sl  = tid >> 4;           // site within block
    const int s   = blockIdx.x * SPB + sl;

    // stage weights to LDS
    for (int idx = tid; idx < NWGT; idx += TPB) wsm[idx] = wgt[idx];

    // ============ phase 1: one transport per thread: t[a*4+i] = U_a W_i(s+a^) U_a^+
    {
        const int a = u, i = g;
        float2 uc[9], wc[9];
        {
            const float2* up = x2 + (s * 8 + a) * 9;
            #pragma unroll
            for (int e = 0; e < 9; e++) uc[e] = up[e];
        }
        const int sn = neigh(s, a);
        {
            const float2* wp = x2 + (sn * 8 + 4 + i) * 9;
            #pragma unroll
            for (int e = 0; e < 9; e++) wc[e] = wp[e];
        }
        // T1 = U * W   (complex):  s += a*b
        float2 t1[9];
        #pragma unroll
        for (int r = 0; r < 3; r++){
            #pragma unroll
            for (int k = 0; k < 3; k++){
                float2 acc = make_float2(0.f, 0.f);
                #pragma unroll
                for (int j = 0; j < 3; j++){
                    float2 a_ = uc[r*3+j], b_ = wc[j*3+k];
                    acc = pk_fma(spl(a_.x), b_, acc);        // (ax*br, ax*bi)
                    acc = pk_fma(np(a_.y), swp(b_), acc);    // (-ay*bi, ay*br)
                }
                t1[r*3+k] = acc;
            }
        }
        // T = T1 * U^+ : T[r,k] = sum_j T1[r,j] * conj(U[k,j])
        float2* dst = &lt[sl * TS2_SITE + (a * 4 + i) * 9];
        #pragma unroll
        for (int r = 0; r < 3; r++){
            #pragma unroll
            for (int k = 0; k < 3; k++){
                float2 acc = make_float2(0.f, 0.f);
                #pragma unroll
                for (int j = 0; j < 3; j++){
                    float2 a_ = t1[r*3+j], b_ = uc[k*3+j];
                    acc = pk_fma(pn(a_.x), b_, acc);         // (ax*br, -ax*bi)
                    acc = pk_fma(spl(a_.y), swp(b_), acc);   // (ay*bi,  ay*br)
                }
                dst[r*3+k] = acc;
            }
        }
    }
    __syncthreads();

    // ============ phase 2 ============
    // pass-through copy of u channels (one quarter of lanes)
    if (g == 1){
        const float2* src = x2 + (s * 8 + u) * 9;
        float2* dst = o2 + (s * 8 + u) * 9;
        #pragma unroll
        for (int e = 0; e < 9; e++) dst[e] = src[e];
    }

    // own-site w matrices -> registers (static indexing only)
    float2 wc[4][9];
    #pragma unroll
    for (int v = 0; v < 4; v++){
        const float2* wp = x2 + (s * 8 + 4 + v) * 9;
        #pragma unroll
        for (int e = 0; e < 9; e++) wc[v][e] = wp[e];
    }

    float2 cc[9];
    #pragma unroll
    for (int e = 0; e < 9; e++) cc[e] = make_float2(0.f, 0.f);

    const float* wu = wsm + u * 297;     // weight[u][v][w], stride 33 per v

    // --- w == 32 identity term: thread's v==g share, static unroll, predicated coef
    {
        #pragma unroll
        for (int v = 0; v < 4; v++){
            float c1 = (v == g) ? wu[v * 33 + 32]       : 0.f;
            float c2 = (v == g) ? wu[(4 + v) * 33 + 32] : 0.f;
            #pragma unroll
            for (int i = 0; i < 3; i++){
                #pragma unroll
                for (int j = 0; j < 3; j++){
                    const int e = i*3+j, eT = j*3+i;
                    cc[e] = pk_fma(spl(c1), wc[v][e],  cc[e]);   // + c1*(wr,wi)
                    cc[e] = pk_fma(pn(c2),  wc[v][eT], cc[e]);   // + (c2*wrT, -c2*wiT)
                }
            }
        }
        if (g == 0){
            float c8 = wu[8 * 33 + 32];
            cc[0].x += c8; cc[4].x += c8; cc[8].x += c8;
        }
    }

    // --- main loop: 4 w16 slots for this thread; N built row-wise (low live set)
    const float2* tbase = &lt[sl * TS2_SITE];
    #pragma unroll
    for (int k = 0; k < 4; k++){
        const int w16 = g * 4 + k;
        float2 tc[9];
        {
            const float2* tp = tbase + w16 * 9;
            #pragma unroll
            for (int e = 0; e < 9; e++) tc[e] = tp[e];
        }

        // ---- pass 1: C += N1 @ T, N1 row i built then consumed immediately
        {
            float cv[9];
            #pragma unroll
            for (int v = 0; v < 9; v++) cv[v] = wu[v * 33 + w16];
            #pragma unroll
            for (int i = 0; i < 3; i++){
                float2 nrow[3];
                #pragma unroll
                for (int j = 0; j < 3; j++){
                    const int e = i*3+j, eT = j*3+i;
                    float2 n = (i == j) ? make_float2(cv[8], 0.f) : make_float2(0.f, 0.f);
                    #pragma unroll
                    for (int v = 0; v < 4; v++){
                        n = pk_fma(spl(cv[v]),   wc[v][e],  n);   // + c*(wr,wi)
                        n = pk_fma(pn(cv[4+v]),  wc[v][eT], n);   // + (c*wrT, -c*wiT)
                    }
                    nrow[j] = n;
                }
                #pragma unroll
                for (int kk = 0; kk < 3; kk++){
                    float2 acc = cc[i*3+kk];
                    #pragma unroll
                    for (int j = 0; j < 3; j++){
                        float2 b_ = tc[j*3+kk];
                        acc = pk_fma(spl(nrow[j].x), b_,      acc); // (nr*br, nr*bi)
                        acc = pk_fma(np(nrow[j].y),  swp(b_), acc); // (-ni*bi, ni*br)
                    }
                    cc[i*3+kk] = acc;
                }
            }
        }

        // ---- pass 2: C += N2 @ T^+, row-wise
        {
            float cv[9];
            #pragma unroll
            for (int v = 0; v < 9; v++) cv[v] = wu[v * 33 + 16 + w16];
            #pragma unroll
            for (int i = 0; i < 3; i++){
                float2 nrow[3];
                #pragma unroll
                for (int j = 0; j < 3; j++){
                    const int e = i*3+j, eT = j*3+i;
                    float2 n = (i == j) ? make_float2(cv[8], 0.f) : make_float2(0.f, 0.f);
                    #pragma unroll
                    for (int v = 0; v < 4; v++){
                        n = pk_fma(spl(cv[v]),   wc[v][e],  n);
                        n = pk_fma(pn(cv[4+v]),  wc[v][eT], n);
                    }
                    nrow[j] = n;
                }
                #pragma unroll
                for (int kk = 0; kk < 3; kk++){
                    float2 acc = cc[i*3+kk];
                    #pragma unroll
                    for (int j = 0; j < 3; j++){
                        // T^+[j,kk] = conj(T[kk,j]) = (b.x, -b.y)
                        float2 b_ = tc[kk*3+j];
                        acc = pk_fma(pn(nrow[j].x),  b_,      acc); // (nr*br, -nr*bi)
                        acc = pk_fma(spl(nrow[j].y), swp(b_), acc); // (ni*bi,  ni*br)
                    }
                    cc[i*3+kk] = acc;
                }
            }
        }
    }

    // --- reduce partials over g (lane bits 0-1) and store
    #pragma unroll
    for (int e = 0; e < 9; e++){
        cc[e].x += __shfl_xor(cc[e].x, 1);
        cc[e].x += __shfl_xor(cc[e].x, 2);
        cc[e].y += __shfl_xor(cc[e].y, 1);
        cc[e].y += __shfl_xor(cc[e].y, 2);
    }
    if (g == 0){
        float2* dst = o2 + (s * 8 + 4 + u) * 9;
        #pragma unroll
        for (int e = 0; e < 9; e++) dst[e] = cc[e];
    }
}

extern "C" void kernel_launch(void* const* d_in, const int* in_sizes, int n_in,
                              void* d_out, int out_size, void* d_ws, size_t ws_size,
                              hipStream_t stream)
{
    const float* x = (const float*)d_in[0];
    const float* w = (const float*)d_in[1];
    float* out = (float*)d_out;
    dim3 grid(NSITES / SPB);
    dim3 block(TPB);
    hipLaunchKernelGGL(gcm_fused, grid, block, 0, stream, x, w, out);
}

// Round 9
// 77.325 us; speedup vs baseline: 1.1501x; 1.1501x over previous
//
#include <hip/hip_runtime.h>
#include <stdint.h>

// GCMConv on MI355X. Data model (verified rounds 0-3):
//   x      : float32 (1,16384,8,3,3,2)  — complex pair = float2
//   weight : float32 (4,9,33)
//   out    : float32 (1,16384,8,3,3,2)
//
// Round-9 M-factorization:  out[u] = sum_{v<9} w_full[v] @ M[u,v],
//   M[u,v] = sum_{w16} ( wt[u,v,w16] t[w16] + wt[u,v,16+w16] t[w16]^+ ) + wt[u,v,32] I
// Thread (u,g) builds M[u,g], M[u,4+g] and its w16-quarter of the v=8 term,
// then cc += w[g] @ M1 + w[g]^+ @ M2; shfl_xor-reduce over g. Live set ~110
// floats (w-replication eliminated) -> 4 waves/SIMD spill-free.

#define SPB 16            // sites per block
#define TPB 256           // 16 threads per site
#define NSITES 16384
#define TS2_SITE 146      // float2 units per site: 16*9 + 2 pad
#define NWGT 1188         // 4*9*33

__device__ __forceinline__ float2 pk_fma(float2 a, float2 b, float2 c){
    return make_float2(fmaf(a.x, b.x, c.x), fmaf(a.y, b.y, c.y));
}
__device__ __forceinline__ float2 spl(float s){ return make_float2(s, s); }
__device__ __forceinline__ float2 pn(float s){ return make_float2(s, -s); }   // (+s,-s)
__device__ __forceinline__ float2 np(float s){ return make_float2(-s, s); }   // (-s,+s)
__device__ __forceinline__ float2 swp(float2 a){ return make_float2(a.y, a.x); }

__device__ __forceinline__ int neigh(int s, int a){
    // dims (8,8,16,16): d3 bits[0:4), d2 bits[4:8), d1 bits[8:11), d0 bits[11:14)
    if (a == 3) return (s & ~15)        | ((s + 1)    & 15);
    if (a == 2) return (s & ~(15 << 4)) | ((s + 16)   & (15 << 4));
    if (a == 1) return (s & ~(7 << 8))  | ((s + 256)  & (7 << 8));
    return              (s & ~(7 << 11))| ((s + 2048) & (7 << 11));
}

__global__ __launch_bounds__(TPB, 2)
void gcm_fused(const float* __restrict__ xp,
               const float* __restrict__ wgt,
               float* __restrict__ outp)
{
    __shared__ float2 lt[SPB * TS2_SITE];
    __shared__ float wsm[NWGT];
    const float2* x2 = (const float2*)xp;
    float2* o2 = (float2*)outp;

    const int tid = threadIdx.x;
    const int g   = tid & 3;            // lane bits 0-1 -> shfl_xor reduction
    const int u   = (tid >> 2) & 3;     // output channel / phase1 axis
    const int sl  = tid >> 4;           // site within block
    const int s   = blockIdx.x * SPB + sl;

    // stage weights to LDS
    for (int idx = tid; idx < NWGT; idx += TPB) wsm[idx] = wgt[idx];

    // ============ phase 1: one transport per thread: t[a*4+i] = U_a W_i(s+a^) U_a^+
    {
        const int a = u, i = g;
        float2 uc[9], wc[9];
        {
            const float2* up = x2 + (s * 8 + a) * 9;
            #pragma unroll
            for (int e = 0; e < 9; e++) uc[e] = up[e];
        }
        const int sn = neigh(s, a);
        {
            const float2* wp = x2 + (sn * 8 + 4 + i) * 9;
            #pragma unroll
            for (int e = 0; e < 9; e++) wc[e] = wp[e];
        }
        // T1 = U * W
        float2 t1[9];
        #pragma unroll
        for (int r = 0; r < 3; r++){
            #pragma unroll
            for (int k = 0; k < 3; k++){
                float2 acc = make_float2(0.f, 0.f);
                #pragma unroll
                for (int j = 0; j < 3; j++){
                    float2 a_ = uc[r*3+j], b_ = wc[j*3+k];
                    acc = pk_fma(spl(a_.x), b_, acc);
                    acc = pk_fma(np(a_.y), swp(b_), acc);
                }
                t1[r*3+k] = acc;
            }
        }
        // T = T1 * U^+ : T[r,k] = sum_j T1[r,j] * conj(U[k,j])
        float2* dst = &lt[sl * TS2_SITE + (a * 4 + i) * 9];
        #pragma unroll
        for (int r = 0; r < 3; r++){
            #pragma unroll
            for (int k = 0; k < 3; k++){
                float2 acc = make_float2(0.f, 0.f);
                #pragma unroll
                for (int j = 0; j < 3; j++){
                    float2 a_ = t1[r*3+j], b_ = uc[k*3+j];
                    acc = pk_fma(pn(a_.x), b_, acc);
                    acc = pk_fma(spl(a_.y), swp(b_), acc);
                }
                dst[r*3+k] = acc;
            }
        }
    }
    __syncthreads();

    // ============ phase 2 ============
    // pass-through copy of u channels (one quarter of lanes)
    if (g == 1){
        const float2* src = x2 + (s * 8 + u) * 9;
        float2* dst = o2 + (s * 8 + u) * 9;
        #pragma unroll
        for (int e = 0; e < 9; e++) dst[e] = src[e];
    }

    // only w[g] needed per thread (18 floats)
    float2 wg[9];
    {
        const float2* wp = x2 + (s * 8 + 4 + g) * 9;
        #pragma unroll
        for (int e = 0; e < 9; e++) wg[e] = wp[e];
    }

    float2 M1[9], M2[9], cc[9];
    #pragma unroll
    for (int e = 0; e < 9; e++){
        M1[e] = make_float2(0.f, 0.f);
        M2[e] = make_float2(0.f, 0.f);
        cc[e] = make_float2(0.f, 0.f);
    }

    const float* wu  = wsm + u * 297;    // weight[u][v][w], stride 33 per v
    const float* wuA = wu + g * 33;      // v = g
    const float* wuB = wu + (4 + g) * 33;// v = 4+g
    const float* wu8 = wu + 8 * 33;      // v = 8

    const float2* tbase = &lt[sl * TS2_SITE];

    // ---- first 4 iters: w16 = 4g+it (this thread's v=8 quarter included)
    #pragma unroll
    for (int it = 0; it < 4; it++){
        const int w16 = g * 4 + it;
        const float2* tp = tbase + w16 * 9;
        float2 tc[9];
        #pragma unroll
        for (int e = 0; e < 9; e++) tc[e] = tp[e];
        float a1 = wuA[w16], b1 = wuA[16 + w16];
        float a2 = wuB[w16], b2 = wuB[16 + w16];
        float c8 = wu8[w16], d8 = wu8[16 + w16];
        #pragma unroll
        for (int i = 0; i < 3; i++){
            #pragma unroll
            for (int j = 0; j < 3; j++){
                const int e = i*3+j, eT = j*3+i;
                M1[e] = pk_fma(spl(a1), tc[e],  M1[e]);
                M1[e] = pk_fma(pn(b1),  tc[eT], M1[e]);
                M2[e] = pk_fma(spl(a2), tc[e],  M2[e]);
                M2[e] = pk_fma(pn(b2),  tc[eT], M2[e]);
                cc[e] = pk_fma(spl(c8), tc[e],  cc[e]);
                cc[e] = pk_fma(pn(d8),  tc[eT], cc[e]);
            }
        }
    }
    // ---- remaining 12 iters: w16 = (4g+4+it) & 15 (no v=8 share)
    #pragma unroll 4
    for (int it = 0; it < 12; it++){
        const int w16 = (g * 4 + 4 + it) & 15;
        const float2* tp = tbase + w16 * 9;
        float2 tc[9];
        #pragma unroll
        for (int e = 0; e < 9; e++) tc[e] = tp[e];
        float a1 = wuA[w16], b1 = wuA[16 + w16];
        float a2 = wuB[w16], b2 = wuB[16 + w16];
        #pragma unroll
        for (int i = 0; i < 3; i++){
            #pragma unroll
            for (int j = 0; j < 3; j++){
                const int e = i*3+j, eT = j*3+i;
                M1[e] = pk_fma(spl(a1), tc[e],  M1[e]);
                M1[e] = pk_fma(pn(b1),  tc[eT], M1[e]);
                M2[e] = pk_fma(spl(a2), tc[e],  M2[e]);
                M2[e] = pk_fma(pn(b2),  tc[eT], M2[e]);
            }
        }
    }

    // ---- identity (w=32) contributions to the diagonals
    {
        float c1 = wuA[32], c2 = wuB[32];
        M1[0].x += c1; M1[4].x += c1; M1[8].x += c1;
        M2[0].x += c2; M2[4].x += c2; M2[8].x += c2;
        if (g == 0){
            float e8 = wu8[32];
            cc[0].x += e8; cc[4].x += e8; cc[8].x += e8;
        }
    }

    // ---- epilogue: cc += w[g] @ M1 + w[g]^+ @ M2
    #pragma unroll
    for (int i = 0; i < 3; i++){
        #pragma unroll
        for (int k = 0; k < 3; k++){
            float2 acc = cc[i*3+k];
            #pragma unroll
            for (int j = 0; j < 3; j++){
                float2 a_ = wg[i*3+j];
                float2 m  = M1[j*3+k];
                acc = pk_fma(spl(a_.x), m,      acc);   // (ax*mr, ax*mi)
                acc = pk_fma(np(a_.y),  swp(m), acc);   // (-ay*mi, ay*mr)
            }
            #pragma unroll
            for (int j = 0; j < 3; j++){
                float2 b_ = wg[j*3+i];                  // conj-transpose source
                float2 m  = M2[j*3+k];
                acc = pk_fma(spl(b_.x), m,      acc);   // (bx*mr, bx*mi)
                acc = pk_fma(pn(b_.y),  swp(m), acc);   // (by*mi, -by*mr)
            }
            cc[i*3+k] = acc;
        }
    }

    // --- reduce partials over g (lane bits 0-1) and store
    #pragma unroll
    for (int e = 0; e < 9; e++){
        cc[e].x += __shfl_xor(cc[e].x, 1);
        cc[e].x += __shfl_xor(cc[e].x, 2);
        cc[e].y += __shfl_xor(cc[e].y, 1);
        cc[e].y += __shfl_xor(cc[e].y, 2);
    }
    if (g == 0){
        float2* dst = o2 + (s * 8 + 4 + u) * 9;
        #pragma unroll
        for (int e = 0; e < 9; e++) dst[e] = cc[e];
    }
}

extern "C" void kernel_launch(void* const* d_in, const int* in_sizes, int n_in,
                              void* d_out, int out_size, void* d_ws, size_t ws_size,
                              hipStream_t stream)
{
    const float* x = (const float*)d_in[0];
    const float* w = (const float*)d_in[1];
    float* out = (float*)d_out;
    dim3 grid(NSITES / SPB);
    dim3 block(TPB);
    hipLaunchKernelGGL(gcm_fused, grid, block, 0, stream, x, w, out);
}

// Round 10
// 76.835 us; speedup vs baseline: 1.1575x; 1.0064x over previous
//
#include <hip/hip_runtime.h>
#include <stdint.h>

// GCMConv on MI355X. Data model (verified rounds 0-3):
//   x      : float32 (1,16384,8,3,3,2)  — complex pair = float2
//   weight : float32 (4,9,33)
//   out    : float32 (1,16384,8,3,3,2)
//
// M-factorization:  out[u] = sum_{v<9} w_full[v] @ M[u,v],
//   M[u,v] = sum_{w16} ( wt[u,v,w16] t[w16] + wt[u,v,16+w16] t[w16]^+ ) + wt[u,v,32] I
// Thread (u,g): builds M[u,g], M[u,4+g], + predicated v=8 quarter; epilogue
// cc += w[g] @ M1 + w[g]^+ @ M2; shfl_xor-reduce over g (lane bits 0-1).
//
// Round-10: M-build ROLLED (#pragma unroll 1). Rounds 7-9 showed kernel time
// tracking static code size, not FMA count (single-batch launch, cold I$,
// ~12-16 KB unrolled body). Rolled loop shrinks code ~4x; body I$-hot from
// iter 2. Private arrays stay statically indexed (w16 only feeds LDS addrs).

#define SPB 16            // sites per block
#define TPB 256           // 16 threads per site
#define NSITES 16384
#define TS2_SITE 146      // float2 units per site: 16*9 + 2 pad
#define NWGT 1188         // 4*9*33

__device__ __forceinline__ float2 pk_fma(float2 a, float2 b, float2 c){
    return make_float2(fmaf(a.x, b.x, c.x), fmaf(a.y, b.y, c.y));
}
__device__ __forceinline__ float2 spl(float s){ return make_float2(s, s); }
__device__ __forceinline__ float2 pn(float s){ return make_float2(s, -s); }   // (+s,-s)
__device__ __forceinline__ float2 np(float s){ return make_float2(-s, s); }   // (-s,+s)
__device__ __forceinline__ float2 swp(float2 a){ return make_float2(a.y, a.x); }

__device__ __forceinline__ int neigh(int s, int a){
    // dims (8,8,16,16): d3 bits[0:4), d2 bits[4:8), d1 bits[8:11), d0 bits[11:14)
    if (a == 3) return (s & ~15)        | ((s + 1)    & 15);
    if (a == 2) return (s & ~(15 << 4)) | ((s + 16)   & (15 << 4));
    if (a == 1) return (s & ~(7 << 8))  | ((s + 256)  & (7 << 8));
    return              (s & ~(7 << 11))| ((s + 2048) & (7 << 11));
}

__global__ __launch_bounds__(TPB, 2)
void gcm_fused(const float* __restrict__ xp,
               const float* __restrict__ wgt,
               float* __restrict__ outp)
{
    __shared__ float2 lt[SPB * TS2_SITE];
    __shared__ float wsm[NWGT];
    const float2* x2 = (const float2*)xp;
    float2* o2 = (float2*)outp;

    const int tid = threadIdx.x;
    const int g   = tid & 3;            // lane bits 0-1 -> shfl_xor reduction
    const int u   = (tid >> 2) & 3;     // output channel / phase1 axis
    const int sl  = tid >> 4;           // site within block
    const int s   = blockIdx.x * SPB + sl;

    // stage weights to LDS (rolled)
    #pragma unroll 1
    for (int idx = tid; idx < NWGT; idx += TPB) wsm[idx] = wgt[idx];

    // ============ phase 1: one transport per thread: t[a*4+i] = U_a W_i(s+a^) U_a^+
    {
        const int a = u, i = g;
        float2 uc[9], wc[9];
        {
            const float2* up = x2 + (s * 8 + a) * 9;
            #pragma unroll
            for (int e = 0; e < 9; e++) uc[e] = up[e];
        }
        const int sn = neigh(s, a);
        {
            const float2* wp = x2 + (sn * 8 + 4 + i) * 9;
            #pragma unroll
            for (int e = 0; e < 9; e++) wc[e] = wp[e];
        }
        // T1 = U * W
        float2 t1[9];
        #pragma unroll
        for (int r = 0; r < 3; r++){
            #pragma unroll
            for (int k = 0; k < 3; k++){
                float2 acc = make_float2(0.f, 0.f);
                #pragma unroll
                for (int j = 0; j < 3; j++){
                    float2 a_ = uc[r*3+j], b_ = wc[j*3+k];
                    acc = pk_fma(spl(a_.x), b_, acc);
                    acc = pk_fma(np(a_.y), swp(b_), acc);
                }
                t1[r*3+k] = acc;
            }
        }
        // T = T1 * U^+ : T[r,k] = sum_j T1[r,j] * conj(U[k,j])
        float2* dst = &lt[sl * TS2_SITE + (a * 4 + i) * 9];
        #pragma unroll
        for (int r = 0; r < 3; r++){
            #pragma unroll
            for (int k = 0; k < 3; k++){
                float2 acc = make_float2(0.f, 0.f);
                #pragma unroll
                for (int j = 0; j < 3; j++){
                    float2 a_ = t1[r*3+j], b_ = uc[k*3+j];
                    acc = pk_fma(pn(a_.x), b_, acc);
                    acc = pk_fma(spl(a_.y), swp(b_), acc);
                }
                dst[r*3+k] = acc;
            }
        }
    }
    __syncthreads();

    // ============ phase 2 ============
    // pass-through copy of u channels (one quarter of lanes)
    if (g == 1){
        const float2* src = x2 + (s * 8 + u) * 9;
        float2* dst = o2 + (s * 8 + u) * 9;
        #pragma unroll
        for (int e = 0; e < 9; e++) dst[e] = src[e];
    }

    float2 M1[9], M2[9], cc[9];
    #pragma unroll
    for (int e = 0; e < 9; e++){
        M1[e] = make_float2(0.f, 0.f);
        M2[e] = make_float2(0.f, 0.f);
        cc[e] = make_float2(0.f, 0.f);
    }

    const float* wu  = wsm + u * 297;    // weight[u][v][w], stride 33 per v
    const float* wuA = wu + g * 33;      // v = g
    const float* wuB = wu + (4 + g) * 33;// v = 4+g
    const float* wu8 = wu + 8 * 33;      // v = 8

    const float2* tbase = &lt[sl * TS2_SITE];

    // ---- M-build: ROLLED 16-iteration loop (code-size critical)
    #pragma unroll 1
    for (int w16 = 0; w16 < 16; w16++){
        const float2* tp = tbase + w16 * 9;
        float2 tc[9];
        #pragma unroll
        for (int e = 0; e < 9; e++) tc[e] = tp[e];
        float a1 = wuA[w16], b1 = wuA[16 + w16];
        float a2 = wuB[w16], b2 = wuB[16 + w16];
        const bool mine = ((w16 >> 2) == g);       // this thread's v=8 quarter
        float c8 = mine ? wu8[w16]      : 0.f;
        float d8 = mine ? wu8[16 + w16] : 0.f;
        #pragma unroll
        for (int i = 0; i < 3; i++){
            #pragma unroll
            for (int j = 0; j < 3; j++){
                const int e = i*3+j, eT = j*3+i;
                M1[e] = pk_fma(spl(a1), tc[e],  M1[e]);
                M1[e] = pk_fma(pn(b1),  tc[eT], M1[e]);
                M2[e] = pk_fma(spl(a2), tc[e],  M2[e]);
                M2[e] = pk_fma(pn(b2),  tc[eT], M2[e]);
                cc[e] = pk_fma(spl(c8), tc[e],  cc[e]);
                cc[e] = pk_fma(pn(d8),  tc[eT], cc[e]);
            }
        }
    }

    // ---- identity (w=32) contributions to the diagonals
    {
        float c1 = wuA[32], c2 = wuB[32];
        M1[0].x += c1; M1[4].x += c1; M1[8].x += c1;
        M2[0].x += c2; M2[4].x += c2; M2[8].x += c2;
        if (g == 0){
            float e8 = wu8[32];
            cc[0].x += e8; cc[4].x += e8; cc[8].x += e8;
        }
    }

    // only w[g] needed per thread (loaded late to keep in-loop pressure low)
    float2 wg[9];
    {
        const float2* wp = x2 + (s * 8 + 4 + g) * 9;
        #pragma unroll
        for (int e = 0; e < 9; e++) wg[e] = wp[e];
    }

    // ---- epilogue: cc += w[g] @ M1 + w[g]^+ @ M2
    #pragma unroll
    for (int i = 0; i < 3; i++){
        #pragma unroll
        for (int k = 0; k < 3; k++){
            float2 acc = cc[i*3+k];
            #pragma unroll
            for (int j = 0; j < 3; j++){
                float2 a_ = wg[i*3+j];
                float2 m  = M1[j*3+k];
                acc = pk_fma(spl(a_.x), m,      acc);   // (ax*mr, ax*mi)
                acc = pk_fma(np(a_.y),  swp(m), acc);   // (-ay*mi, ay*mr)
            }
            #pragma unroll
            for (int j = 0; j < 3; j++){
                float2 b_ = wg[j*3+i];                  // conj-transpose source
                float2 m  = M2[j*3+k];
                acc = pk_fma(spl(b_.x), m,      acc);   // (bx*mr, bx*mi)
                acc = pk_fma(pn(b_.y),  swp(m), acc);   // (by*mi, -by*mr)
            }
            cc[i*3+k] = acc;
        }
    }

    // --- reduce partials over g (lane bits 0-1) and store
    #pragma unroll
    for (int e = 0; e < 9; e++){
        cc[e].x += __shfl_xor(cc[e].x, 1);
        cc[e].x += __shfl_xor(cc[e].x, 2);
        cc[e].y += __shfl_xor(cc[e].y, 1);
        cc[e].y += __shfl_xor(cc[e].y, 2);
    }
    if (g == 0){
        float2* dst = o2 + (s * 8 + 4 + u) * 9;
        #pragma unroll
        for (int e = 0; e < 9; e++) dst[e] = cc[e];
    }
}

extern "C" void kernel_launch(void* const* d_in, const int* in_sizes, int n_in,
                              void* d_out, int out_size, void* d_ws, size_t ws_size,
                              hipStream_t stream)
{
    const float* x = (const float*)d_in[0];
    const float* w = (const float*)d_in[1];
    float* out = (float*)d_out;
    dim3 grid(NSITES / SPB);
    dim3 block(TPB);
    hipLaunchKernelGGL(gcm_fused, grid, block, 0, stream, x, w, out);
}